// Round 8
// baseline (429.247 us; speedup 1.0000x reference)
//
#include <hip/hip_runtime.h>
#include <hip/hip_bf16.h>
#include <math.h>

#define B_  128
#define L_  196
#define F_  2048
#define H_  512
#define A_  512
#define ML_ (B_*L_)   // 25088 rows = 196 tiles of 128 exactly

typedef _Float16 half8 __attribute__((ext_vector_type(8)));
typedef _Float16 half4v __attribute__((ext_vector_type(4)));
typedef _Float16 half2v __attribute__((ext_vector_type(2)));
typedef float f32x4 __attribute__((ext_vector_type(4)));

// async 16B global->LDS (LDS dest = wave-uniform base + lane*16)
__device__ __forceinline__ void gld_lds16(const void* g, void* l) {
  __builtin_amdgcn_global_load_lds((const __attribute__((address_space(1))) void*)g,
                                   (__attribute__((address_space(3))) void*)l, 16, 0, 0);
}

// ---------------------------------------------------------------------------
// K_prep: 256 blocks (was 128 = half GPU idle). Block bid: cvt 1024 float4 of
// Wenc fp32->f16; b = bid>>1, half = bid&1 -> 256 dec rows per block.
// ---------------------------------------------------------------------------
__global__ __launch_bounds__(256) void k_prep(const float4* __restrict__ Wenc4,
                                              half4v* __restrict__ wH,
                                              const float* __restrict__ hs,
                                              const float* __restrict__ Wdec,
                                              const float* __restrict__ bdec,
                                              const float* __restrict__ benc,
                                              float* __restrict__ dec,
                                              float* __restrict__ scores) {
  const int bid = blockIdx.x, t = threadIdx.x;
  const int b = bid >> 1, half = bid & 1;

  {
    const int base = bid * 1024 + t;
    float4 v[4];
#pragma unroll
    for (int j = 0; j < 4; j++) v[j] = Wenc4[base + j * 256];
#pragma unroll
    for (int j = 0; j < 4; j++) {
      half4v o = { (_Float16)v[j].x, (_Float16)v[j].y, (_Float16)v[j].z, (_Float16)v[j].w };
      wH[base + j * 256] = o;
    }
  }

  const int g = bid * 256 + t;
  if (g < ML_) scores[g] = 0.f;

  __shared__ float h[H_];
  h[t]       = hs[b * H_ + t];
  h[t + 256] = hs[b * H_ + t + 256];
  __syncthreads();

  {
    const int a = half * 256 + t;
    float acc = bdec[a] + benc[a];
    const float4* wr = (const float4*)(Wdec + (size_t)a * H_);
#pragma unroll 4
    for (int k4 = 0; k4 < H_ / 4; k4++) {
      const float4 w = wr[k4];
      acc += w.x * h[4*k4] + w.y * h[4*k4+1] + w.z * h[4*k4+2] + w.w * h[4*k4+3];
    }
    dec[b * A_ + a] = acc;
  }
}

// ---------------------------------------------------------------------------
// K2 (MFMA): scores[m] += sum_a relu(feat[m,:]·Wenc[a,:] + dec[b,a]) * wcom[a]
//   R8 == R7 resubmit (container infra failure, no measurement):
//   CONCURRENCY play. Three different schedules (R1/R4/R6) all tied at
//   147-186us with MfmaUtil ~14%, occ ~17% -> latency-bound, starved at
//   3 blocks/CU (grid 784 = 3.06/CU; 50KB LDS; 152 combined regs).
//   Fix: split N=512 into 8 a-tiles of 64 (legal: a-sum is linear after
//   relu; K cannot be split) -> grid 1568 (6.1/CU). acc [4][2] = 32 AGPR,
//   LDS = As 16KB (single, reg-prefetched A) + Bs 2x8KB (gld_lds dbuf)
//   = 32KB exactly -> 4 blocks/CU = 16 waves/CU (launch_bounds (256,4)).
//   Per step: issue B(s+1) -> cvt+write A(s) [compiler's fr-wait retires
//   B(s), keeps B(s+1)] -> issue fr(s+1) -> lgkmcnt(0) only -> barrier ->
//   16 MFMA -> barrier. No vmcnt(0) in loop.
//   Swizzles (proven in R6, conflicts 8K): As write b64 slot8 = g8^((r&7)<<1),
//   read b128 slot = g^(row&7); Bs pre-swizzled global src, slot = g^(row&7).
//   XCD decode: all 8 a-blocks of one m-tile -> same XCD (A-tile L2 reuse x8).
// ---------------------------------------------------------------------------
__global__ __launch_bounds__(256, 4) void k_scores_mfma(const float* __restrict__ fA,
                                                        const _Float16* __restrict__ fB,
                                                        const float* __restrict__ dec,
                                                        const float* __restrict__ wcom,
                                                        float* __restrict__ scores) {
  __shared__ _Float16  As[128 * 64];      // f16, 16KB
  __shared__ _Float16  Bs[2][64 * 64];    // f16, 2x8KB

  const int tid  = threadIdx.x;
  const int lane = tid & 63;
  const int w    = tid >> 6;

  // XCD-aware decode: ids of one m-tile's 8 a-blocks differ by 8.
  const int l = blockIdx.x;
  int mt, c;
  if (l < 1536) { mt = (l >> 6) * 8 + (l & 7); c = (l >> 3) & 7; }
  else { const int idx = l - 1536; mt = 192 + (idx & 3); c = idx >> 2; }
  const int a0 = c * 64;
  const int m0 = mt * 128;

  const int wm   = w & 1;
  const int wn   = w >> 1;
  const int quad = lane >> 4;
  const int l16  = lane & 15;

  f32x4 acc[4][2];
#pragma unroll
  for (int i = 0; i < 4; i++)
#pragma unroll
    for (int j = 0; j < 2; j++)
#pragma unroll
      for (int k = 0; k < 4; k++) acc[i][j][k] = 0.f;

  // A staging (R6 geometry): chunk i covers rows w*32 + i*4 + (lane>>4),
  // cols (lane&15)*4 -> 4 coalesced 256B segments per dwordx4.
  const int arow4 = lane >> 4;
  const int acol  = (lane & 15) * 4;
  const float* pA = fA + (size_t)(m0 + w * 32 + arow4) * F_ + acol;
  const int g8    = lane & 15;

  // B staging: 2 issues/wave/step; issue i = rows w*16 + i*8 + (lane>>3);
  // LDS slot lane&7 holds granule (lane&7)^(row&7); row&7 == lane>>3.
  const int srowB = lane >> 3;
  const _Float16* pB = fB + (size_t)(a0 + w * 16 + srowB) * F_
                          + (size_t)(((lane & 7) ^ srowB) * 8);

  // prologue: B(0) -> Bs[0] (issued FIRST: oldest in queue), then A(0) -> regs
#pragma unroll
  for (int i = 0; i < 2; i++)
    gld_lds16(pB + (size_t)(i * 8) * F_, &Bs[0][(w * 16 + i * 8) * 64]);
  float4 fr[8];
#pragma unroll
  for (int i = 0; i < 8; i++)
    fr[i] = *(const float4*)(pA + (size_t)(i * 4) * F_);

  for (int s = 0; s < 32; ++s) {
    const int kt  = s * 64;
    const int buf = s & 1;
    // (a) B(s+1) -> other buffer (before cvt so fr-wait keeps it in flight)
    if (s < 31) {
#pragma unroll
      for (int i = 0; i < 2; i++)
        gld_lds16(pB + (size_t)(i * 8) * F_ + kt + 64,
                  &Bs[buf ^ 1][(w * 16 + i * 8) * 64]);
    }
    // (b) cvt + swizzled ds_write of A(s); compiler waits fr(s) -> retires
    // B(s) (older) as a side effect, keeps B(s+1) in flight.
#pragma unroll
    for (int i = 0; i < 8; i++) {
      const int r = w * 32 + i * 4 + arow4;
      half4v h;
      half2v h0 = (half2v)__builtin_amdgcn_cvt_pkrtz(fr[i].x, fr[i].y);
      half2v h1 = (half2v)__builtin_amdgcn_cvt_pkrtz(fr[i].z, fr[i].w);
      h[0] = h0[0]; h[1] = h0[1]; h[2] = h1[0]; h[3] = h1[1];
      *(half4v*)&As[r * 64 + (g8 ^ ((r & 7) << 1)) * 4] = h;
    }
    // (c) A(s+1) -> regs (lands under MFMA phase)
    if (s < 31) {
#pragma unroll
      for (int i = 0; i < 8; i++)
        fr[i] = *(const float4*)(pA + (size_t)(i * 4) * F_ + kt + 64);
    }
    // (d) only LDS-writes need draining; B(s) already retired at (b)
    asm volatile("s_waitcnt lgkmcnt(0)" ::: "memory");
    __builtin_amdgcn_s_barrier();
    __builtin_amdgcn_sched_barrier(0);

#pragma unroll
    for (int kk = 0; kk < 2; kk++) {
      half8 af[4], bf[2];
#pragma unroll
      for (int mf = 0; mf < 4; mf++) {
        const int row = wm * 64 + mf * 16 + l16;
        af[mf] = *(const half8*)&As[row * 64 + (((kk * 4 + quad)) ^ (row & 7)) * 8];
      }
#pragma unroll
      for (int at = 0; at < 2; at++) {
        const int row = wn * 32 + at * 16 + l16;
        bf[at] = *(const half8*)&Bs[buf][row * 64 + (((kk * 4 + quad)) ^ (row & 7)) * 8];
      }
#pragma unroll
      for (int mf = 0; mf < 4; mf++)
#pragma unroll
        for (int at = 0; at < 2; at++)
          acc[mf][at] = __builtin_amdgcn_mfma_f32_16x16x32_f16(af[mf], bf[at], acc[mf][at], 0, 0, 0);
    }

    __builtin_amdgcn_sched_barrier(0);
    __builtin_amdgcn_s_barrier();   // all waves done reading As/Bs[buf]
    __builtin_amdgcn_sched_barrier(0);
  }

  float w2[2];
#pragma unroll
  for (int at = 0; at < 2; at++) w2[at] = wcom[a0 + wn * 32 + at * 16 + l16];

#pragma unroll
  for (int mf = 0; mf < 4; mf++) {
#pragma unroll
    for (int r = 0; r < 4; r++) {
      const int m  = m0 + wm * 64 + mf * 16 + quad * 4 + r;  // C/D: row=(lane>>4)*4+reg
      const int bb = m / L_;
      float p = 0.f;
#pragma unroll
      for (int at = 0; at < 2; at++) {
        const float e = acc[mf][at][r] + dec[bb * A_ + a0 + wn * 32 + at * 16 + l16];
        p = fmaf(fmaxf(e, 0.f), w2[at], p);
      }
      p += __shfl_xor(p, 1);
      p += __shfl_xor(p, 2);
      p += __shfl_xor(p, 4);
      p += __shfl_xor(p, 8);
      if (l16 == 0) atomicAdd(&scores[m], p);
    }
  }
}

// ---------------------------------------------------------------------------
// K_softmax: alpha[b,:] = softmax(scores[b,:]). 128 blocks x 256 thr, ~2us.
// ---------------------------------------------------------------------------
__global__ __launch_bounds__(256) void k_softmax(const float* __restrict__ scores,
                                                 float* __restrict__ alpha) {
  const int b = blockIdx.x, t = threadIdx.x;
  __shared__ float redm[4];
  __shared__ float reds[4];

  float s = (t < L_) ? scores[b * L_ + t] : -INFINITY;
  float m = s;
#pragma unroll
  for (int o = 32; o >= 1; o >>= 1) m = fmaxf(m, __shfl_xor(m, o));
  if ((t & 63) == 0) redm[t >> 6] = m;
  __syncthreads();
  m = fmaxf(fmaxf(redm[0], redm[1]), fmaxf(redm[2], redm[3]));
  float e = (t < L_) ? expf(s - m) : 0.f;
  float sum = e;
#pragma unroll
  for (int o = 32; o >= 1; o >>= 1) sum += __shfl_xor(sum, o);
  if ((t & 63) == 0) reds[t >> 6] = sum;
  __syncthreads();
  sum = reds[0] + reds[1] + reds[2] + reds[3];
  if (t < L_) alpha[b * L_ + t] = e / sum;
}

// ---------------------------------------------------------------------------
// K_attn: pure weighted sum over fp32 feat, reading precomputed alpha.
// grid (8 f-chunks, B) x 128 threads; two independent row streams.
// ---------------------------------------------------------------------------
__global__ __launch_bounds__(128) void k_attn_f32(const float* __restrict__ feat,
                                                  const float* __restrict__ alpha,
                                                  float* __restrict__ out) {
  const int fc = blockIdx.x, b = blockIdx.y, t = threadIdx.x;
  __shared__ float al[L_];

  al[t] = alpha[b * L_ + t];
  if (t < L_ - 128) al[t + 128] = alpha[b * L_ + t + 128];
  __syncthreads();

  const int f0 = fc * 256 + t * 2;
  const float2* fp = (const float2*)(feat + (size_t)b * L_ * F_ + f0);
  float a0x = 0.f, a0y = 0.f, a1x = 0.f, a1y = 0.f;
#pragma unroll 7
  for (int ll = 0; ll < 98; ll++) {
    const float2 v0 = fp[(size_t)ll * (F_ / 2)];
    const float2 v1 = fp[(size_t)(ll + 98) * (F_ / 2)];
    const float w0 = al[ll];
    const float w1 = al[ll + 98];
    a0x = fmaf(v0.x, w0, a0x);
    a0y = fmaf(v0.y, w0, a0y);
    a1x = fmaf(v1.x, w1, a1x);
    a1y = fmaf(v1.y, w1, a1y);
  }
  float2 o = { a0x + a1x, a0y + a1y };
  *(float2*)(out + (size_t)b * F_ + f0) = o;
}

// ---------------------------------------------------------------------------
// Fallback fp32 GEMM path (ws too small — effectively never taken)
// ---------------------------------------------------------------------------
__global__ __launch_bounds__(256) void k_scores_f32(const float* __restrict__ feat,
                                                    const float* __restrict__ Wenc,
                                                    const float* __restrict__ dec,
                                                    const float* __restrict__ wcom,
                                                    float* __restrict__ scores) {
  __shared__ float As[16][128];
  __shared__ float Bs[16][128];
  const int tid = threadIdx.x;
  const int m0 = blockIdx.x * 128;
  const int a0 = blockIdx.y * 128;
  const int tx = tid & 15;
  const int ty = tid >> 4;
  float acc[8][8];
#pragma unroll
  for (int i = 0; i < 8; i++)
#pragma unroll
    for (int j = 0; j < 8; j++) acc[i][j] = 0.f;
  for (int kt = 0; kt < F_; kt += 16) {
#pragma unroll
    for (int rep = 0; rep < 2; rep++) {
      const int idx = rep * 256 + tid;
      const int row = idx >> 2;
      const int kp  = (idx & 3) << 2;
      const float4 v = *(const float4*)(feat + (size_t)(m0 + row) * F_ + kt + kp);
      As[kp+0][row] = v.x; As[kp+1][row] = v.y; As[kp+2][row] = v.z; As[kp+3][row] = v.w;
      const float4 w = *(const float4*)(Wenc + (size_t)(a0 + row) * F_ + kt + kp);
      Bs[kp+0][row] = w.x; Bs[kp+1][row] = w.y; Bs[kp+2][row] = w.z; Bs[kp+3][row] = w.w;
    }
    __syncthreads();
#pragma unroll
    for (int k = 0; k < 16; k++) {
      float ar[8], br[8];
      *(float4*)&ar[0] = *(const float4*)&As[k][ty * 8];
      *(float4*)&ar[4] = *(const float4*)&As[k][ty * 8 + 4];
      *(float4*)&br[0] = *(const float4*)&Bs[k][tx * 8];
      *(float4*)&br[4] = *(const float4*)&Bs[k][tx * 8 + 4];
#pragma unroll
      for (int i = 0; i < 8; i++)
#pragma unroll
        for (int j = 0; j < 8; j++) acc[i][j] = fmaf(ar[i], br[j], acc[i][j]);
    }
    __syncthreads();
  }
  float w8[8];
  *(float4*)&w8[0] = *(const float4*)(wcom + a0 + tx * 8);
  *(float4*)&w8[4] = *(const float4*)(wcom + a0 + tx * 8 + 4);
#pragma unroll
  for (int i = 0; i < 8; i++) {
    const int m = m0 + ty * 8 + i;
    const int b = m / L_;
    const float* dp = dec + b * A_ + a0 + tx * 8;
    float p = 0.f;
#pragma unroll
    for (int j = 0; j < 8; j++) {
      const float e = acc[i][j] + dp[j];
      p = fmaf(fmaxf(e, 0.f), w8[j], p);
    }
    p += __shfl_xor(p, 1);
    p += __shfl_xor(p, 2);
    p += __shfl_xor(p, 4);
    p += __shfl_xor(p, 8);
    if (tx == 0) atomicAdd(&scores[m], p);
  }
}

__global__ __launch_bounds__(256) void k_dec_only(const float* __restrict__ hs,
                                                  const float* __restrict__ Wdec,
                                                  const float* __restrict__ bdec,
                                                  const float* __restrict__ benc,
                                                  float* __restrict__ dec,
                                                  float* __restrict__ scores) {
  const int b = blockIdx.x, t = threadIdx.x;
  const int g = b * 256 + t;
  if (g < ML_) scores[g] = 0.f;
  __shared__ float h[H_];
  h[t]       = hs[b * H_ + t];
  h[t + 256] = hs[b * H_ + t + 256];
  __syncthreads();
#pragma unroll
  for (int r = 0; r < 2; r++) {
    const int a = t + r * 256;
    float acc = bdec[a] + benc[a];
    const float4* wr = (const float4*)(Wdec + (size_t)a * H_);
#pragma unroll 4
    for (int k4 = 0; k4 < H_ / 4; k4++) {
      const float4 w = wr[k4];
      acc += w.x * h[4*k4] + w.y * h[4*k4+1] + w.z * h[4*k4+2] + w.w * h[4*k4+3];
    }
    dec[b * A_ + a] = acc;
  }
}

// ---------------------------------------------------------------------------
extern "C" void kernel_launch(void* const* d_in, const int* in_sizes, int n_in,
                              void* d_out, int out_size, void* d_ws, size_t ws_size,
                              hipStream_t stream) {
  const float* feat = (const float*)d_in[0];   // [B,L,F]
  const float* hs   = (const float*)d_in[1];   // [B,H]
  const float* Wenc = (const float*)d_in[2];   // [A,F]
  const float* benc = (const float*)d_in[3];   // [A]
  const float* Wdec = (const float*)d_in[4];   // [A,H]
  const float* bdec = (const float*)d_in[5];   // [A]
  const float* wcom = (const float*)d_in[6];   // [1,A]
  // d_in[7] = b_com: softmax-invariant, unused

  float* out   = (float*)d_out;                // [B*F] weighted ++ [B*L] alpha
  float* alpha = out + B_ * F_;
  float* dec    = (float*)d_ws;                // [B*A]
  float* scores = dec + B_ * A_;               // [B*L]

  const size_t need = (size_t)(B_ * A_ + ML_) * 4 + (size_t)A_ * F_ * 2;

  if (ws_size >= need) {
    _Float16* wH = (_Float16*)(scores + ML_);  // [A_, F_] f16
    k_prep<<<dim3(256), dim3(256), 0, stream>>>(
        (const float4*)Wenc, (half4v*)wH, hs, Wdec, bdec, benc, dec, scores);
    k_scores_mfma<<<dim3(1568), dim3(256), 0, stream>>>(feat, wH, dec, wcom, scores);
  } else {
    k_dec_only<<<dim3(B_), dim3(256), 0, stream>>>(hs, Wdec, bdec, benc, dec, scores);
    k_scores_f32<<<dim3(ML_ / 128, A_ / 128), dim3(256), 0, stream>>>(feat, Wenc, dec, wcom, scores);
  }
  k_softmax<<<dim3(B_), dim3(256), 0, stream>>>(scores, alpha);
  k_attn_f32<<<dim3(8, B_), dim3(128), 0, stream>>>(feat, alpha, out);
}